// Round 12
// baseline (62.647 us; speedup 1.0000x reference)
//
#include <hip/hip_runtime.h>

typedef __attribute__((ext_vector_type(8))) short bf16x8;
typedef __attribute__((ext_vector_type(4))) float f32x4;
typedef __attribute__((ext_vector_type(2))) float f32x2;

__device__ __forceinline__ f32x2 fma2(f32x2 a, f32x2 b, f32x2 c) {
    return __builtin_elementwise_fma(a, b, c);   // llvm.fma.v2f32 -> v_pk_fma_f32
}

// quad_perm DPP (VALU cross-lane). CTRL = perm[0]|perm[1]<<2|perm[2]<<4|perm[3]<<6
// 0x141 = row_half_mirror (lane i -> i^7 within each octet).
template <int CTRL>
__device__ __forceinline__ float qperm(float x) {
    return __builtin_bit_cast(float,
        __builtin_amdgcn_update_dpp(0, __builtin_bit_cast(int, x), CTRL, 0xf, 0xf, true));
}
template <int CTRL>
__device__ __forceinline__ f32x2 qperm2(f32x2 x) {
    f32x2 r;
    r.x = qperm<CTRL>(x.x);
    r.y = qperm<CTRL>(x.y);
    return r;
}

// Fused: quantum-head encode + 8x8 head-attention + scrambled reshape + 64x64 combine.
// Lane map: lane = kch(2b) : G1(1b) : h(3b); each aligned 8-lane group = one token's
// 8 heads; each lane's attention output IS its MFMA A-fragment slot.
// R12 = R11 with the nt-load type fixed (ext_vector f32x4, not HIP float4).
// NON-TEMPORAL x loads: x is read-once per replay; out is rewritten every replay.
// x+out = 265MB > 256MB L3 -> both thrash. nt x-reads stop x from allocating in
// L3, letting out (131MB) stay resident -> HBM writebacks collapse. (nt STORES
// are unsafe here - R7 - but nt LOADS are a pure cache hint, correctness-safe.)
__global__ __launch_bounds__(256) void qattn(const float* __restrict__ x,
                                             const float* __restrict__ theta,
                                             const float* __restrict__ wc,
                                             const float* __restrict__ bc,
                                             float* __restrict__ out)
{
    // [snt=4*s+nt][lane][8] ushorts, 8 KB each; fragments pre-permuted so the
    // b128 read addr = base + lane*16 (linear, wave-uniform base).
    __shared__ __align__(16) unsigned short sWhi[512 * 8];
    __shared__ __align__(16) unsigned short sWlo[512 * 8];

    const float KAPPA = 0.71419161f;        // sqrt(2^-1.5 * log2(e))
    const float INVK  = 1.40018590f;        // 1/KAPPA
    const float INV2PI = 0.15915494309189535f;

    const int tid = threadIdx.x;
    #pragma unroll
    for (int f0 = 0; f0 < 2; ++f0) {
        const int f = tid * 2 + f0;          // 0..511
        const int snt = f >> 6, ln = f & 63;
        const int s = snt >> 2, nt = snt & 3;
        const int r = nt * 16 + (ln & 15);
        const int koff = s * 32 + (ln >> 4) * 8;
        const float* wp = wc + r * 64 + koff;
        float w8[8];
        *(f32x4*)(&w8[0]) = *(const f32x4*)(wp);
        *(f32x4*)(&w8[4]) = *(const f32x4*)(wp + 4);
        #pragma unroll
        for (int j = 0; j < 8; ++j) {
            float w = w8[j] * INVK;          // fold 1/kappa into W
            unsigned u = __builtin_bit_cast(unsigned, w);
            sWhi[f * 8 + j] = (unsigned short)(u >> 16);
            float rhi = __builtin_bit_cast(float, u & 0xffff0000u);
            unsigned l = __builtin_bit_cast(unsigned, w - rhi);
            sWlo[f * 8 + j] = (unsigned short)(l >> 16);
        }
    }
    __syncthreads();

    const int lane = tid & 63;
    const int wid  = tid >> 6;
    const int h    = lane & 7;
    const int G1   = (lane >> 3) & 1;
    const int kch  = lane >> 4;
    const int col  = lane & 15;
    const int fby  = lane * 8;

    // theta/(2pi) packed pairs
    f32x2 th2p[4];
    #pragma unroll
    for (int j = 0; j < 4; ++j) {
        th2p[j].x = theta[2 * j] * INV2PI;
        th2p[j].y = theta[2 * j + 1] * INV2PI;
    }
    float bs[4];
    #pragma unroll
    for (int nt = 0; nt < 4; ++nt) bs[nt] = bc[nt * 16 + col];

    const int P0 = (int)blockIdx.x * 4 + wid;            // 0..16383
    const float* xp0 = x + ((size_t)((2 * P0 + G1) * 8 + kch)) * 64 + h * 8;
    const size_t IT_STRIDE = (size_t)16384 * 16 * 64;    // pairs * tokens * E

    f32x4 cur[4];
    cur[0] = __builtin_nontemporal_load((const f32x4*)(xp0));
    cur[1] = __builtin_nontemporal_load((const f32x4*)(xp0 + 4));
    cur[2] = __builtin_nontemporal_load((const f32x4*)(xp0 + 256));
    cur[3] = __builtin_nontemporal_load((const f32x4*)(xp0 + 260));

    #pragma unroll
    for (int it = 0; it < 2; ++it) {
        f32x4 nxt[4];
        if (it < 1) {
            const float* p = xp0 + IT_STRIDE;
            nxt[0] = __builtin_nontemporal_load((const f32x4*)(p));
            nxt[1] = __builtin_nontemporal_load((const f32x4*)(p + 4));
            nxt[2] = __builtin_nontemporal_load((const f32x4*)(p + 256));
            nxt[3] = __builtin_nontemporal_load((const f32x4*)(p + 260));
        }

        const int P = it * 16384 + P0;   // group-pair 0..32767

        bf16x8 ahi[2], alo[2];
        #pragma unroll
        for (int s = 0; s < 2; ++s) {
            // angle in revolutions: a = fma(v, 1/2pi, th/2pi), packed
            const f32x2* v2 = (const f32x2*)&cur[s * 2];
            f32x2 inv2 = {INV2PI, INV2PI};
            float c[8];
            #pragma unroll
            for (int j = 0; j < 4; ++j) {
                f32x2 a2 = fma2(v2[j], inv2, th2p[j]);
                c[2 * j]     = __builtin_amdgcn_cosf(__builtin_amdgcn_fractf(a2.x));
                c[2 * j + 1] = __builtin_amdgcn_cosf(__builtin_amdgcn_fractf(a2.y));
            }
            c[1] *= KAPPA;   // every z contains c1 -> scales all z by kappa

            // z[0] = c1..c7 ; z[k] = c0..ck (k>=1)   (all pre-scaled by kappa)
            float z[8];
            z[1] = c[0] * c[1];
            #pragma unroll
            for (int d = 2; d < 8; ++d) z[d] = z[d - 1] * c[d];
            float p = c[1];
            #pragma unroll
            for (int d = 2; d < 8; ++d) p *= c[d];
            z[0] = p;

            f32x2 z2[4];
            #pragma unroll
            for (int j = 0; j < 4; ++j) { z2[j].x = z[2 * j]; z2[j].y = z[2 * j + 1]; }

            // partner at t = h^7 via row_half_mirror
            f32x2 z72[4];
            #pragma unroll
            for (int j = 0; j < 4; ++j) z72[j] = qperm2<0x141>(z2[j]);

            f32x2 osum2[4];
            #pragma unroll
            for (int j = 0; j < 4; ++j) osum2[j] = (f32x2){0.f, 0.f};
            float esum = 0.f;

            // packed softmax-PV step vs partner pair-vector zt2
            #define QSTEP(ZT)                                                      \
                do {                                                               \
                    f32x2 s2 = (ZT)[0] * z2[0];                                    \
                    s2 = fma2((ZT)[1], z2[1], s2);                                 \
                    s2 = fma2((ZT)[2], z2[2], s2);                                 \
                    s2 = fma2((ZT)[3], z2[3], s2);                                 \
                    float e = __builtin_amdgcn_exp2f(s2.x + s2.y);                 \
                    esum += e;                                                     \
                    f32x2 e2 = {e, e};                                             \
                    _Pragma("unroll")                                              \
                    for (int j = 0; j < 4; ++j)                                    \
                        osum2[j] = fma2(e2, (ZT)[j], osum2[j]);                    \
                } while (0)

            QSTEP(z2);                                           // m=0
            {
                f32x2 w2[4];
                #pragma unroll
                for (int j = 0; j < 4; ++j) w2[j] = qperm2<0xB1>(z2[j]);   // m=1
                QSTEP(w2);
                #pragma unroll
                for (int j = 0; j < 4; ++j) w2[j] = qperm2<0x4E>(z2[j]);   // m=2
                QSTEP(w2);
                #pragma unroll
                for (int j = 0; j < 4; ++j) w2[j] = qperm2<0x1B>(z2[j]);   // m=3
                QSTEP(w2);
            }
            QSTEP(z72);                                          // m=7
            {
                f32x2 w2[4];
                #pragma unroll
                for (int j = 0; j < 4; ++j) w2[j] = qperm2<0xB1>(z72[j]);  // m=6
                QSTEP(w2);
                #pragma unroll
                for (int j = 0; j < 4; ++j) w2[j] = qperm2<0x4E>(z72[j]);  // m=5
                QSTEP(w2);
                #pragma unroll
                for (int j = 0; j < 4; ++j) w2[j] = qperm2<0x1B>(z72[j]);  // m=4
                QSTEP(w2);
            }
            #undef QSTEP

            float r = __builtin_amdgcn_rcpf(esum);
            f32x2 r2 = {r, r};
            f32x2 o2[4];
            #pragma unroll
            for (int j = 0; j < 4; ++j) o2[j] = osum2[j] * r2;

            // truncation hi/lo split + pair pack: hi=RTZ(o), lo=RTZ(o-hi) (exact residual)
            unsigned hp[4], lp[4];
            #pragma unroll
            for (int pq = 0; pq < 4; ++pq) {
                unsigned e0 = __builtin_bit_cast(unsigned, o2[pq].x);
                unsigned e1 = __builtin_bit_cast(unsigned, o2[pq].y);
                hp[pq] = (e0 >> 16) | (e1 & 0xffff0000u);
                float r0 = __builtin_bit_cast(float, e0 & 0xffff0000u);
                float r1 = __builtin_bit_cast(float, e1 & 0xffff0000u);
                unsigned l0 = __builtin_bit_cast(unsigned, o2[pq].x - r0);
                unsigned l1 = __builtin_bit_cast(unsigned, o2[pq].y - r1);
                lp[pq] = (l0 >> 16) | (l1 & 0xffff0000u);
            }
            ahi[s] = __builtin_bit_cast(bf16x8, *(const unsigned(*)[4])hp);
            alo[s] = __builtin_bit_cast(bf16x8, *(const unsigned(*)[4])lp);
        }

        #pragma unroll
        for (int q = 0; q < 4; ++q) cur[q] = nxt[q];

        // Y(16x64) = G(16x64) @ (W/k)^T via 4 n-tiles x 2 k-chunks x 3 passes (hi/lo).
        f32x4 acc[4];
        #pragma unroll
        for (int nt = 0; nt < 4; ++nt) acc[nt] = (f32x4){0.f, 0.f, 0.f, 0.f};
        #pragma unroll
        for (int nt = 0; nt < 4; ++nt) {
            #pragma unroll
            for (int s = 0; s < 2; ++s) {
                const int off = (s * 4 + nt) * 512 + fby;
                bf16x8 bhi = *(const bf16x8*)(&sWhi[off]);
                bf16x8 blo = *(const bf16x8*)(&sWlo[off]);
                acc[nt] = __builtin_amdgcn_mfma_f32_16x16x32_bf16(ahi[s], bhi, acc[nt], 0, 0, 0);
                acc[nt] = __builtin_amdgcn_mfma_f32_16x16x32_bf16(alo[s], bhi, acc[nt], 0, 0, 0);
                acc[nt] = __builtin_amdgcn_mfma_f32_16x16x32_bf16(ahi[s], blo, acc[nt], 0, 0, 0);
            }
        }

        // C/D: col = lane&15, row = (lane>>4)*4 + q ; row -> (G1', h'),
        // output row = b*8192 + h'*1024 + g_in_batch.
        #pragma unroll
        for (int q = 0; q < 4; ++q) {
            const int r16 = kch * 4 + q;
            const int hh = r16 & 7;
            const int gg = r16 >> 3;
            const int gf2 = 2 * P + gg;
            const int orow = (gf2 >> 10) * 8192 + hh * 1024 + (gf2 & 1023);
            float* op = out + orow * 64 + col;
            #pragma unroll
            for (int nt = 0; nt < 4; ++nt)
                op[nt * 16] = acc[nt][q] + bs[nt];
        }
    }
}

extern "C" void kernel_launch(void* const* d_in, const int* in_sizes, int n_in,
                              void* d_out, int out_size, void* d_ws, size_t ws_size,
                              hipStream_t stream) {
    const float* x     = (const float*)d_in[0];
    const float* theta = (const float*)d_in[1];
    const float* wc    = (const float*)d_in[2];
    const float* bc    = (const float*)d_in[3];
    float* out = (float*)d_out;
    qattn<<<dim3(4096), dim3(256), 0, stream>>>(x, theta, wc, bc, out);
}

// Round 13
// 52.011 us; speedup vs baseline: 1.2045x; 1.2045x over previous
//
#include <hip/hip_runtime.h>

typedef __attribute__((ext_vector_type(8))) short bf16x8;
typedef __attribute__((ext_vector_type(4))) float f32x4;

// quad_perm DPP (VALU cross-lane, no DS pipe). CTRL = perm[0]|perm[1]<<2|perm[2]<<4|perm[3]<<6
// Also: 0x141 = row_half_mirror (lane i -> i^7 within each octet).
template <int CTRL>
__device__ __forceinline__ float qperm(float x) {
    return __builtin_bit_cast(float,
        __builtin_amdgcn_update_dpp(0, __builtin_bit_cast(int, x), CTRL, 0xf, 0xf, true));
}

// Fused: quantum-head encode + 8x8 head-attention + scrambled reshape + 64x64 combine.
// R13 = exact restore of R5 (best measured: 52.24us).
// Lane map (per wave): lane = kch(2b) : G1(1b) : h(3b); each aligned 8-lane group = one
// token's 8 heads, and each lane's attention output IS its MFMA A-fragment slot.
// Attention partner traversal in XOR order, all cross-lane via DPP (VALU pipe):
//   m=0..3: quad_perm of z; m=7..4: quad_perm of z7 = row_half_mirror(z) (xor-7).
// W staged in LDS pre-permuted into MFMA B-fragment order: read addr = base + lane*16
// (linear -> zero bank conflicts, wave-uniform base). Software-pipelined x loads
// (full unroll, prefetch depth 1); trunc-split bf16 hi/lo 3-pass MFMA; v_exp_f32.
//
// Structural floor (8-variant ledger): 197MB mandatory HBM (66R after ~50% L3 + 131W)
// ~31us + ~21us irreducible VALU with ~zero overlap at this pattern = ~52us.
// Invariant under DS elimination, VALU packing, MLP depth, granularity, sync removal,
// occupancy 24-50%, and both nt cache policies (loads regress, stores corrupt).
__global__ __launch_bounds__(256) void qattn(const float* __restrict__ x,
                                             const float* __restrict__ theta,
                                             const float* __restrict__ wc,
                                             const float* __restrict__ bc,
                                             float* __restrict__ out)
{
    // [snt=4*s+nt][lane][8] ushorts, 8 KB each
    __shared__ __align__(16) unsigned short sWhi[512 * 8];
    __shared__ __align__(16) unsigned short sWlo[512 * 8];

    const int tid = threadIdx.x;
    // stage W as pre-permuted fragments: frag f=(snt*64+lane) holds W row nt*16+(lane&15),
    // k-cols [s*32+(lane>>4)*8 .. +8), trunc hi/lo split (lo = exact residual).
    #pragma unroll
    for (int f0 = 0; f0 < 2; ++f0) {
        const int f = tid * 2 + f0;          // 0..511
        const int snt = f >> 6, ln = f & 63;
        const int s = snt >> 2, nt = snt & 3;
        const int r = nt * 16 + (ln & 15);
        const int koff = s * 32 + (ln >> 4) * 8;
        const float* wp = wc + r * 64 + koff;
        float w8[8];
        *(float4*)(&w8[0]) = *(const float4*)(wp);
        *(float4*)(&w8[4]) = *(const float4*)(wp + 4);
        #pragma unroll
        for (int j = 0; j < 8; ++j) {
            unsigned u = __builtin_bit_cast(unsigned, w8[j]);
            sWhi[f * 8 + j] = (unsigned short)(u >> 16);
            float rhi = __builtin_bit_cast(float, u & 0xffff0000u);
            unsigned l = __builtin_bit_cast(unsigned, w8[j] - rhi);
            sWlo[f * 8 + j] = (unsigned short)(l >> 16);
        }
    }
    __syncthreads();

    const int lane = tid & 63;
    const int wid  = tid >> 6;
    const int h    = lane & 7;          // head (A-frag row low bits)
    const int G1   = (lane >> 3) & 1;   // group bit (A-frag row high bit)
    const int kch  = lane >> 4;         // k-chunk = token-within-half-group
    const int col  = lane & 15;         // MFMA C/D column
    const int fby  = lane * 8;          // fragment ushort offset within a snt block

    float th[8];
    #pragma unroll
    for (int d = 0; d < 8; ++d) th[d] = theta[d];
    float bs[4];
    #pragma unroll
    for (int nt = 0; nt < 4; ++nt) bs[nt] = bc[nt * 16 + col];

    const int P0 = (int)blockIdx.x * 4 + wid;           // group-pair for it=0
    const float* xp0 = x + ((size_t)((2 * P0 + G1) * 8 + kch)) * 64 + h * 8;
    const size_t IT_STRIDE = (size_t)8192 * 16 * 64;    // per-it: 8192 pairs * 16 tok * 64

    float4 cur[4];
    cur[0] = *(const float4*)(xp0);
    cur[1] = *(const float4*)(xp0 + 4);
    cur[2] = *(const float4*)(xp0 + 256);
    cur[3] = *(const float4*)(xp0 + 260);

    #pragma unroll
    for (int it = 0; it < 4; ++it) {
        float4 nxt[4];
        if (it < 3) {
            const float* p = xp0 + (size_t)(it + 1) * IT_STRIDE;
            nxt[0] = *(const float4*)(p);
            nxt[1] = *(const float4*)(p + 4);
            nxt[2] = *(const float4*)(p + 256);
            nxt[3] = *(const float4*)(p + 260);
        }

        const int P = it * 8192 + P0;   // group-pair 0..32767

        bf16x8 ahi[2], alo[2];
        #pragma unroll
        for (int s = 0; s < 2; ++s) {
            float v[8];
            *(float4*)(&v[0]) = cur[s * 2 + 0];
            *(float4*)(&v[4]) = cur[s * 2 + 1];

            float c[8];
            #pragma unroll
            for (int d = 0; d < 8; ++d) c[d] = __cosf(v[d] + th[d]);

            // z[0] = c1..c7 ; z[k] = c0..ck (k>=1)
            float z[8];
            z[1] = c[0] * c[1];
            #pragma unroll
            for (int d = 2; d < 8; ++d) z[d] = z[d - 1] * c[d];
            float p = c[1];
            #pragma unroll
            for (int d = 2; d < 8; ++d) p *= c[d];
            z[0] = p;

            // z7 = partner vector at t = h^7 (row_half_mirror), pure DPP
            float z7[8];
            #pragma unroll
            for (int d = 0; d < 8; ++d) z7[d] = qperm<0x141>(z[d]);

            float osum[8];
            #pragma unroll
            for (int d = 0; d < 8; ++d) osum[d] = 0.f;
            float esum = 0.f;

            // one softmax-PV step vs partner vector zt (t = h^m); alpha*log2(e) folded
            #define QSTEP(ZT0,ZT1,ZT2,ZT3,ZT4,ZT5,ZT6,ZT7)                         \
                do {                                                               \
                    float zt_[8] = {ZT0,ZT1,ZT2,ZT3,ZT4,ZT5,ZT6,ZT7};              \
                    float sc = zt_[0] * z[0];                                      \
                    _Pragma("unroll")                                              \
                    for (int d = 1; d < 8; ++d) sc = fmaf(zt_[d], z[d], sc);       \
                    float e = __builtin_amdgcn_exp2f(0.51006978f * sc);            \
                    esum += e;                                                     \
                    _Pragma("unroll")                                              \
                    for (int d = 0; d < 8; ++d) osum[d] = fmaf(e, zt_[d], osum[d]);\
                } while (0)

            QSTEP(z[0],z[1],z[2],z[3],z[4],z[5],z[6],z[7]);                 // m=0
            {
                float t0[8], t1[8], t2[8];
                #pragma unroll
                for (int d = 0; d < 8; ++d) t0[d] = qperm<0xB1>(z[d]);      // m=1
                QSTEP(t0[0],t0[1],t0[2],t0[3],t0[4],t0[5],t0[6],t0[7]);
                #pragma unroll
                for (int d = 0; d < 8; ++d) t1[d] = qperm<0x4E>(z[d]);      // m=2
                QSTEP(t1[0],t1[1],t1[2],t1[3],t1[4],t1[5],t1[6],t1[7]);
                #pragma unroll
                for (int d = 0; d < 8; ++d) t2[d] = qperm<0x1B>(z[d]);      // m=3
                QSTEP(t2[0],t2[1],t2[2],t2[3],t2[4],t2[5],t2[6],t2[7]);
            }
            QSTEP(z7[0],z7[1],z7[2],z7[3],z7[4],z7[5],z7[6],z7[7]);         // m=7
            {
                float t0[8], t1[8], t2[8];
                #pragma unroll
                for (int d = 0; d < 8; ++d) t0[d] = qperm<0xB1>(z7[d]);     // m=6
                QSTEP(t0[0],t0[1],t0[2],t0[3],t0[4],t0[5],t0[6],t0[7]);
                #pragma unroll
                for (int d = 0; d < 8; ++d) t1[d] = qperm<0x4E>(z7[d]);     // m=5
                QSTEP(t1[0],t1[1],t1[2],t1[3],t1[4],t1[5],t1[6],t1[7]);
                #pragma unroll
                for (int d = 0; d < 8; ++d) t2[d] = qperm<0x1B>(z7[d]);     // m=4
                QSTEP(t2[0],t2[1],t2[2],t2[3],t2[4],t2[5],t2[6],t2[7]);
            }
            #undef QSTEP

            float r = __builtin_amdgcn_rcpf(esum);
            float o[8];
            #pragma unroll
            for (int d = 0; d < 8; ++d) o[d] = osum[d] * r;

            // truncation hi/lo split + pair pack: hi=RTZ(o), lo=RTZ(o-hi)
            unsigned hp[4], lp[4];
            #pragma unroll
            for (int pq = 0; pq < 4; ++pq) {
                unsigned e0 = __builtin_bit_cast(unsigned, o[2 * pq]);
                unsigned e1 = __builtin_bit_cast(unsigned, o[2 * pq + 1]);
                hp[pq] = (e0 >> 16) | (e1 & 0xffff0000u);
                float r0 = __builtin_bit_cast(float, e0 & 0xffff0000u);
                float r1 = __builtin_bit_cast(float, e1 & 0xffff0000u);
                unsigned l0 = __builtin_bit_cast(unsigned, o[2 * pq] - r0);
                unsigned l1 = __builtin_bit_cast(unsigned, o[2 * pq + 1] - r1);
                lp[pq] = (l0 >> 16) | (l1 & 0xffff0000u);
            }
            ahi[s] = __builtin_bit_cast(bf16x8, *(const unsigned(*)[4])hp);
            alo[s] = __builtin_bit_cast(bf16x8, *(const unsigned(*)[4])lp);
        }

        #pragma unroll
        for (int q = 0; q < 4; ++q) cur[q] = nxt[q];

        // Y(16x64) = G(16x64) @ W^T via 4 n-tiles x 2 k-chunks x 3 passes (hi/lo).
        // B-fragment reads are linear in lane (zero conflicts, wave-uniform base).
        f32x4 acc[4];
        #pragma unroll
        for (int nt = 0; nt < 4; ++nt) acc[nt] = (f32x4){0.f, 0.f, 0.f, 0.f};
        #pragma unroll
        for (int nt = 0; nt < 4; ++nt) {
            #pragma unroll
            for (int s = 0; s < 2; ++s) {
                const int off = (s * 4 + nt) * 512 + fby;
                bf16x8 bhi = *(const bf16x8*)(&sWhi[off]);
                bf16x8 blo = *(const bf16x8*)(&sWlo[off]);
                acc[nt] = __builtin_amdgcn_mfma_f32_16x16x32_bf16(ahi[s], bhi, acc[nt], 0, 0, 0);
                acc[nt] = __builtin_amdgcn_mfma_f32_16x16x32_bf16(alo[s], bhi, acc[nt], 0, 0, 0);
                acc[nt] = __builtin_amdgcn_mfma_f32_16x16x32_bf16(ahi[s], blo, acc[nt], 0, 0, 0);
            }
        }

        // C/D: col = lane&15, row = (lane>>4)*4 + q ; row -> (G1', h'),
        // output row = b*8192 + h'*1024 + g_in_batch.
        #pragma unroll
        for (int q = 0; q < 4; ++q) {
            const int r16 = kch * 4 + q;
            const int hh = r16 & 7;
            const int gg = r16 >> 3;
            const int gf2 = 2 * P + gg;
            const int orow = (gf2 >> 10) * 8192 + hh * 1024 + (gf2 & 1023);
            float* op = out + orow * 64 + col;
            #pragma unroll
            for (int nt = 0; nt < 4; ++nt)
                op[nt * 16] = acc[nt][q] + bs[nt];
        }
    }
}

extern "C" void kernel_launch(void* const* d_in, const int* in_sizes, int n_in,
                              void* d_out, int out_size, void* d_ws, size_t ws_size,
                              hipStream_t stream) {
    const float* x     = (const float*)d_in[0];
    const float* theta = (const float*)d_in[1];
    const float* wc    = (const float*)d_in[2];
    const float* bc    = (const float*)d_in[3];
    float* out = (float*)d_out;
    qattn<<<dim3(2048), dim3(256), 0, stream>>>(x, theta, wc, bc, out);
}